// Round 2
// baseline (117.068 us; speedup 1.0000x reference)
//
#include <hip/hip_runtime.h>
#include <hip/hip_bf16.h>

// Masked SDPA, B=16, NQ=NKV=2048, D=64. Inputs/out are FLOAT32 on device
// (per reference dtypes); compute path converts to bf16 for MFMA, f32 accum.
// Flash-attention forward: 1 wave = 16 q-rows, KV tiles of 32, online softmax.
// valid_lens masking: KV tiles past valid_len skipped; valid_len==0 -> uniform
// weights over all 2048 (matches softmax of all -1e20).

typedef __attribute__((ext_vector_type(8))) short short8;
typedef __attribute__((ext_vector_type(4))) float float4v;

#define BATCH 16
#define NQ 2048
#define NKV 2048
#define DH 64
#define NEG_INF -1e20f

// f32 -> bf16 (round-nearest-even), bit form
__device__ __forceinline__ short f2bf(float x) {
    union { float f; unsigned u; } v; v.f = x;
    unsigned r = (v.u + 0x7fffu + ((v.u >> 16) & 1u)) >> 16;
    return (short)r;
}

// load 8 consecutive f32, convert to bf16x8 fragment
__device__ __forceinline__ short8 load_cvt8(const float* p) {
    float4v a = *reinterpret_cast<const float4v*>(p);
    float4v b = *reinterpret_cast<const float4v*>(p + 4);
    short8 r;
    r[0] = f2bf(a[0]); r[1] = f2bf(a[1]); r[2] = f2bf(a[2]); r[3] = f2bf(a[3]);
    r[4] = f2bf(b[0]); r[5] = f2bf(b[1]); r[6] = f2bf(b[2]); r[7] = f2bf(b[3]);
    return r;
}

__global__ __launch_bounds__(256) void attn_fwd_kernel(
    const float* __restrict__ Q,
    const float* __restrict__ K,
    const float* __restrict__ V,
    const int* __restrict__ valid_lens,
    float* __restrict__ O)
{
    __shared__ short lds_p[4][16][32];  // per-wave P tile (16q x 32kv), bf16 bits

    const int tid  = threadIdx.x;
    const int wave = tid >> 6;
    const int lane = tid & 63;
    const int l15  = lane & 15;
    const int l4   = lane >> 4;

    const int qtiles = NQ / 64;                 // 32 blocks of 64 q-rows per batch
    const int b  = blockIdx.x / qtiles;
    const int qt = blockIdx.x % qtiles;
    const int qbase = qt * 64 + wave * 16;

    const int vlen = valid_lens[b];
    const int nkv_eff = (vlen == 0) ? NKV : vlen;   // all-masked -> full loop
    const int niter = (nkv_eff + 31) >> 5;

    const float* Qb = Q + ((size_t)b * NQ + qbase) * DH;
    const float* Kb = K + (size_t)b * NKV * DH;
    const float* Vb = V + (size_t)b * NKV * DH;

    // Q A-fragments: lane holds row (lane&15), k-dim d = h*32 + (lane>>4)*8 + j
    short8 qfrag[2];
#pragma unroll
    for (int h = 0; h < 2; ++h)
        qfrag[h] = load_cvt8(Qb + (size_t)l15 * DH + h * 32 + l4 * 8);

    float4v acc_o[4];
#pragma unroll
    for (int t = 0; t < 4; ++t) acc_o[t] = float4v{0.f, 0.f, 0.f, 0.f};
    float m[4], lsum[4];
#pragma unroll
    for (int r = 0; r < 4; ++r) { m[r] = -INFINITY; lsum[r] = 0.f; }

    for (int it = 0; it < niter; ++it) {
        const int kvbase = it * 32;

        // ---- S = (Q K^T) * scale for 16x32 tile: two 16x16 sub-tiles ----
        float4v acc_s[2];
        acc_s[0] = float4v{0.f, 0.f, 0.f, 0.f};
        acc_s[1] = float4v{0.f, 0.f, 0.f, 0.f};
#pragma unroll
        for (int s = 0; s < 2; ++s) {
#pragma unroll
            for (int h = 0; h < 2; ++h) {
                // B-fragment of K^T: lane holds col kv=(lane&15), k-dim d
                short8 kf = load_cvt8(
                    Kb + (size_t)(kvbase + s * 16 + l15) * DH + h * 32 + l4 * 8);
                acc_s[s] = __builtin_amdgcn_mfma_f32_16x16x32_bf16(
                    qfrag[h], kf, acc_s[s], 0, 0, 0);
            }
        }

        // ---- scale + mask ----
        float sv[2][4];
#pragma unroll
        for (int s = 0; s < 2; ++s) {
            const int kv = kvbase + s * 16 + l15;
            const bool valid = kv < vlen;       // vlen==0 -> all masked
#pragma unroll
            for (int r = 0; r < 4; ++r) {
                float x = acc_s[s][r] * 0.125f;
                sv[s][r] = valid ? x : NEG_INF;
            }
        }

        // ---- online softmax: row max over 32 cols (16 lanes x 2 subtiles) ----
        float alpha[4];
#pragma unroll
        for (int r = 0; r < 4; ++r) {
            float x = fmaxf(sv[0][r], sv[1][r]);
#pragma unroll
            for (int off = 1; off < 16; off <<= 1)
                x = fmaxf(x, __shfl_xor(x, off, 64));
            const float mn = fmaxf(m[r], x);
            alpha[r] = expf(m[r] - mn);         // m=-inf first iter -> 0
            m[r] = mn;
        }

        float rsum[4] = {0.f, 0.f, 0.f, 0.f};
#pragma unroll
        for (int s = 0; s < 2; ++s) {
#pragma unroll
            for (int r = 0; r < 4; ++r) {
                const float p = expf(sv[s][r] - m[r]);
                sv[s][r] = p;
                rsum[r] += p;
            }
        }
#pragma unroll
        for (int r = 0; r < 4; ++r) {
            float x = rsum[r];
#pragma unroll
            for (int off = 1; off < 16; off <<= 1)
                x += __shfl_xor(x, off, 64);
            lsum[r] = lsum[r] * alpha[r] + x;
        }
#pragma unroll
        for (int t = 0; t < 4; ++t)
#pragma unroll
            for (int r = 0; r < 4; ++r)
                acc_o[t][r] *= alpha[r];

        // ---- P -> bf16 via per-wave LDS (C/D layout -> A layout) ----
#pragma unroll
        for (int s = 0; s < 2; ++s)
#pragma unroll
            for (int r = 0; r < 4; ++r)
                lds_p[wave][l4 * 4 + r][s * 16 + l15] = f2bf(sv[s][r]);
        // in-wave write->read: force DS completion + forbid reordering
        asm volatile("s_waitcnt lgkmcnt(0)" ::: "memory");
        // A-fragment read: row = lane&15, cols (lane>>4)*8 .. +7 (16B contiguous)
        short8 pf = *reinterpret_cast<const short8*>(&lds_p[wave][l15][l4 * 8]);

        // ---- O += P V (K=32 over kv tile) ----
#pragma unroll
        for (int t = 0; t < 4; ++t) {
            short8 vf;
#pragma unroll
            for (int j = 0; j < 8; ++j) {
                vf[j] = f2bf(Vb[(size_t)(kvbase + l4 * 8 + j) * DH + t * 16 + l15]);
            }
            acc_o[t] = __builtin_amdgcn_mfma_f32_16x16x32_bf16(
                pf, vf, acc_o[t], 0, 0, 0);
        }
    }

    // ---- epilogue: O / lsum, f32 store ----
    float* Ob = O + ((size_t)b * NQ + qbase) * DH;
#pragma unroll
    for (int t = 0; t < 4; ++t) {
#pragma unroll
        for (int r = 0; r < 4; ++r) {
            const float v = acc_o[t][r] / lsum[r];
            Ob[(size_t)(l4 * 4 + r) * DH + t * 16 + l15] = v;
        }
    }
}

extern "C" void kernel_launch(void* const* d_in, const int* in_sizes, int n_in,
                              void* d_out, int out_size, void* d_ws, size_t ws_size,
                              hipStream_t stream) {
    const float* Q = (const float*)d_in[0];
    const float* K = (const float*)d_in[1];
    const float* V = (const float*)d_in[2];
    const int* vl  = (const int*)d_in[3];
    float* Out     = (float*)d_out;

    dim3 grid(BATCH * (NQ / 64));
    dim3 block(256);
    attn_fwd_kernel<<<grid, block, 0, stream>>>(Q, K, V, vl, Out);
}

// Round 3
// 82.498 us; speedup vs baseline: 1.4190x; 1.4190x over previous
//
#include <hip/hip_runtime.h>
#include <hip/hip_bf16.h>

// Masked SDPA, B=16, NQ=NKV=2048, D=64, f32 in/out, bf16 MFMA compute.
// R3: block-cooperative bf16 LDS staging (K swizzled row-major, V transposed+
// swizzled), KVBLK=64, async stage split (T14), exp2-based online softmax.
// Block = 4 waves x 16 q-rows = 64 q-rows. Grid = 16 batches x 32 q-tiles,
// batch index fastest for better makespan under valid_lens imbalance.

typedef __attribute__((ext_vector_type(8))) short short8;
typedef __attribute__((ext_vector_type(4))) short short4v;
typedef __attribute__((ext_vector_type(4))) float float4v;

#define BATCH 16
#define NQ 2048
#define NKV 2048
#define DH 64
#define KVB 64
#define NEG_INF -1e20f
// 0.125 (=1/sqrt(64)) * log2(e): softmax in base-2 is identical math
#define SCALE_LOG2 0.180336880111120f

// f32 -> bf16 (round-nearest-even), bit form
__device__ __forceinline__ short f2bf(float x) {
    union { float f; unsigned u; } v; v.f = x;
    unsigned r = (v.u + 0x7fffu + ((v.u >> 16) & 1u)) >> 16;
    return (short)r;
}

__device__ __forceinline__ short8 cvt8(float4v a, float4v b) {
    short8 r;
    r[0] = f2bf(a[0]); r[1] = f2bf(a[1]); r[2] = f2bf(a[2]); r[3] = f2bf(a[3]);
    r[4] = f2bf(b[0]); r[5] = f2bf(b[1]); r[6] = f2bf(b[2]); r[7] = f2bf(b[3]);
    return r;
}

__global__ __launch_bounds__(256) void attn_fwd_kernel(
    const float* __restrict__ Q,
    const float* __restrict__ K,
    const float* __restrict__ V,
    const int* __restrict__ valid_lens,
    float* __restrict__ O)
{
    __shared__ short k_lds[KVB * DH];      // K tile [kv][d], swizzled
    __shared__ short vt_lds[DH * KVB];     // V^T tile [d][kv], swizzled
    __shared__ short p_lds[4][16 * KVB];   // per-wave P tile [q][kv], swizzled

    const int tid  = threadIdx.x;
    const int wave = tid >> 6;
    const int lane = tid & 63;
    const int l15  = lane & 15;
    const int l4   = lane >> 4;

    const int b  = blockIdx.x & 15;        // batch fastest
    const int qt = blockIdx.x >> 4;        // 0..31
    const int qbase = qt * 64 + wave * 16;

    const int vlen = valid_lens[b];
    const int nkv  = (vlen == 0) ? NKV : vlen;   // all-masked -> uniform over all
    const int niter = (nkv + KVB - 1) / KVB;

    const float* Qb = Q + ((size_t)b * NQ + qbase) * DH;
    const float* Kb = K + (size_t)b * NKV * DH;
    const float* Vb = V + (size_t)b * NKV * DH;

    // Q A-fragments: lane row (lane&15), k-elems d = h*32 + (lane>>4)*8 + j
    short8 qfrag[2];
#pragma unroll
    for (int h = 0; h < 2; ++h) {
        const float* p = Qb + (size_t)l15 * DH + h * 32 + l4 * 8;
        qfrag[h] = cvt8(*reinterpret_cast<const float4v*>(p),
                        *reinterpret_cast<const float4v*>(p + 4));
    }

    // staging coordinates
    const int krow = tid >> 2;             // 0..63
    const int kcol = (tid & 3) << 4;       // 0,16,32,48
    const int vkv  = (tid >> 4) << 2;      // 0..60 step 4
    const int vd   = (tid & 15) << 2;      // 0..60 step 4

    float4v kr[4], vr[4];

    auto load_tile = [&](int kvbase) {
        const float* kp = Kb + (size_t)(kvbase + krow) * DH + kcol;
#pragma unroll
        for (int i = 0; i < 4; ++i)
            kr[i] = *reinterpret_cast<const float4v*>(kp + i * 4);
        const float* vp = Vb + (size_t)(kvbase + vkv) * DH + vd;
#pragma unroll
        for (int i = 0; i < 4; ++i)
            vr[i] = *reinterpret_cast<const float4v*>(vp + (size_t)i * DH);
    };

    auto store_tile = [&]() {
        const int ksw = (krow & 7) << 3;
        short8 w0 = cvt8(kr[0], kr[1]);
        short8 w1 = cvt8(kr[2], kr[3]);
        *reinterpret_cast<short8*>(&k_lds[krow * DH + (kcol ^ ksw)]) = w0;
        *reinterpret_cast<short8*>(&k_lds[krow * DH + ((kcol + 8) ^ ksw)]) = w1;
#pragma unroll
        for (int k = 0; k < 4; ++k) {
            const int d = vd + k;
            short4v w;
            w[0] = f2bf(vr[0][k]); w[1] = f2bf(vr[1][k]);
            w[2] = f2bf(vr[2][k]); w[3] = f2bf(vr[3][k]);
            *reinterpret_cast<short4v*>(
                &vt_lds[d * KVB + (vkv ^ ((d & 7) << 3))]) = w;
        }
    };

    float4v acc_o[4];
#pragma unroll
    for (int t = 0; t < 4; ++t) acc_o[t] = float4v{0.f, 0.f, 0.f, 0.f};
    float m[4], lsum[4];
#pragma unroll
    for (int r = 0; r < 4; ++r) { m[r] = -INFINITY; lsum[r] = 0.f; }

    // prologue: stage tile 0
    load_tile(0);
    store_tile();
    __syncthreads();

    const int rsw = (l15 & 7) << 3;        // read-side swizzle (row&7 == l15&7)

    for (int it = 0; it < niter; ++it) {
        const int kvbase = it * KVB;
        const bool more = (it + 1 < niter);
        if (more) load_tile(kvbase + KVB);  // T14: issue early, write late

        // ---- S = (Q K^T) * scale: 4 subtiles of 16 kv ----
        float4v acc_s[4];
#pragma unroll
        for (int s = 0; s < 4; ++s) acc_s[s] = float4v{0.f, 0.f, 0.f, 0.f};
#pragma unroll
        for (int s = 0; s < 4; ++s) {
            const short* kb = &k_lds[(s * 16 + l15) * DH];
#pragma unroll
            for (int h = 0; h < 2; ++h) {
                short8 kf = *reinterpret_cast<const short8*>(
                    &kb[(h * 32 + l4 * 8) ^ rsw]);
                acc_s[s] = __builtin_amdgcn_mfma_f32_16x16x32_bf16(
                    qfrag[h], kf, acc_s[s], 0, 0, 0);
            }
        }

        // ---- scale (log2 units) + mask ----
        float sv[4][4];
#pragma unroll
        for (int s = 0; s < 4; ++s) {
            const bool valid = (kvbase + s * 16 + l15) < vlen;
#pragma unroll
            for (int r = 0; r < 4; ++r)
                sv[s][r] = valid ? acc_s[s][r] * SCALE_LOG2 : NEG_INF;
        }

        // ---- online softmax (base 2) ----
        float alpha[4];
#pragma unroll
        for (int r = 0; r < 4; ++r) {
            float x = fmaxf(fmaxf(sv[0][r], sv[1][r]),
                            fmaxf(sv[2][r], sv[3][r]));
#pragma unroll
            for (int off = 1; off < 16; off <<= 1)
                x = fmaxf(x, __shfl_xor(x, off, 64));
            const float mn = fmaxf(m[r], x);
            alpha[r] = exp2f(m[r] - mn);   // m=-inf first iter -> 0
            m[r] = mn;
        }
        float rs[4] = {0.f, 0.f, 0.f, 0.f};
#pragma unroll
        for (int s = 0; s < 4; ++s)
#pragma unroll
            for (int r = 0; r < 4; ++r) {
                const float p = exp2f(sv[s][r] - m[r]);
                sv[s][r] = p;
                rs[r] += p;
            }
#pragma unroll
        for (int r = 0; r < 4; ++r) {
            float x = rs[r];
#pragma unroll
            for (int off = 1; off < 16; off <<= 1)
                x += __shfl_xor(x, off, 64);
            lsum[r] = lsum[r] * alpha[r] + x;
        }
#pragma unroll
        for (int t = 0; t < 4; ++t)
#pragma unroll
            for (int r = 0; r < 4; ++r)
                acc_o[t][r] *= alpha[r];

        // ---- P -> bf16 via per-wave swizzled LDS (C/D -> A layout) ----
        short* pw = p_lds[wave];
#pragma unroll
        for (int s = 0; s < 4; ++s)
#pragma unroll
            for (int r = 0; r < 4; ++r) {
                const int row = l4 * 4 + r;
                pw[row * KVB + ((s * 16 + l15) ^ ((row & 7) << 3))] =
                    f2bf(sv[s][r]);
            }
        asm volatile("s_waitcnt lgkmcnt(0)" ::: "memory");
        short8 pf[2];
#pragma unroll
        for (int ks = 0; ks < 2; ++ks)
            pf[ks] = *reinterpret_cast<const short8*>(
                &pw[l15 * KVB + ((ks * 32 + l4 * 8) ^ rsw)]);

        // ---- O += P V ----
#pragma unroll
        for (int t = 0; t < 4; ++t) {
            const short* vb2 = &vt_lds[(t * 16 + l15) * KVB];
#pragma unroll
            for (int ks = 0; ks < 2; ++ks) {
                short8 vf = *reinterpret_cast<const short8*>(
                    &vb2[(ks * 32 + l4 * 8) ^ rsw]);
                acc_o[t] = __builtin_amdgcn_mfma_f32_16x16x32_bf16(
                    pf[ks], vf, acc_o[t], 0, 0, 0);
            }
        }

        __syncthreads();                   // all K/V LDS reads done
        if (more) store_tile();            // T14: write late
        __syncthreads();                   // staged writes visible
    }

    // ---- epilogue: O / lsum, f32 store ----
    float* Ob = O + ((size_t)b * NQ + qbase) * DH;
#pragma unroll
    for (int t = 0; t < 4; ++t)
#pragma unroll
        for (int r = 0; r < 4; ++r)
            Ob[(size_t)(l4 * 4 + r) * DH + t * 16 + l15] =
                acc_o[t][r] / lsum[r];
}

extern "C" void kernel_launch(void* const* d_in, const int* in_sizes, int n_in,
                              void* d_out, int out_size, void* d_ws, size_t ws_size,
                              hipStream_t stream) {
    const float* Q = (const float*)d_in[0];
    const float* K = (const float*)d_in[1];
    const float* V = (const float*)d_in[2];
    const int* vl  = (const int*)d_in[3];
    float* Out     = (float*)d_out;

    dim3 grid(BATCH * (NQ / 64));
    dim3 block(256);
    attn_fwd_kernel<<<grid, block, 0, stream>>>(Q, K, V, vl, Out);
}